// Round 18
// baseline (178.173 us; speedup 1.0000x reference)
//
#include <hip/hip_runtime.h>
#include <hip/hip_bf16.h>

#define B_TOT 131072
#define D     32
#define H1    50
#define QF    528      // tril feature count
#define H2    700
#define MROWS 64       // batch rows per block
#define QSTR  584      // quadls row stride (ushorts), 1168 B = 73*16
#define KSTEPS 36      // K = 576 in steps of 16 (32x32x16 MFMA)
#define NTILE  24      // 768 hidden cols / 32
// extended hidden layout (768 cols): 0..699 net2 hidden, 700..749 net1 hidden,
// 750 bias channel (h==1.0), 751..767 zero pad. K = 576 = 528 quad | 1 | 32 y | 15 pad.

typedef __attribute__((ext_vector_type(8)))  short  short8x;
typedef __attribute__((ext_vector_type(4)))  float  floatx4;
typedef __attribute__((ext_vector_type(16))) float  floatx16;
typedef __attribute__((ext_vector_type(4)))  unsigned short ushort4x;

static __device__ __forceinline__ unsigned short f2bf(float f) {
    __hip_bfloat16 h = __float2bfloat16(f);   // RNE
    return __builtin_bit_cast(unsigned short, h);
}
static __device__ __forceinline__ float bf2f(unsigned short u) {
    unsigned int x = (unsigned int)u << 16;
    return __builtin_bit_cast(float, x);
}
// clampless tanh; MUST stay bit-identical between prep (bias channel) and epilogue.
static __device__ __forceinline__ float tanh_fast(float x) {
    float e = __builtin_amdgcn_exp2f(x * 2.885390082f);   // e^(2x)
    return 1.f - 2.f * __builtin_amdgcn_rcpf(e + 1.f);
}

// ---------------- prep: 32x32x16-fragment bf16 weight layouts ----------------
// W2aT: [kstep 0..35][tile 0..23][lane 0..63][j 0..7]  (442368 ushorts)
//   B1[kk][c]: kk = kstep*16 + (lane>>5)*8 + j, c = tile*32 + (lane&31)
//   value: c<700: kk<528->W2a[kk][c], kk==528->b2a[c];
//          c<750: kk==528->b1a[c-700], 529<=kk<561->W1a[kk-529][c-700];
//          c==750: kk==528->1.0; else 0
// W2bT: [wave w 0..7][s 0..5][lane][j]  (24576 ushorts)
//   B2[kg][c]: kg = w*96 + s*16 + (lane>>5)*8 + j, c = lane&31
//   value: kg<700->W2b; kg<750->W1b[kg-700]; kg==750->(b1b+b2b)/tanh_fast(1); else 0
__global__ void prep_kernel(const float* __restrict__ W2a, const float* __restrict__ b2a,
                            const float* __restrict__ W2b,
                            const float* __restrict__ W1a, const float* __restrict__ b1a,
                            const float* __restrict__ W1b, const float* __restrict__ b1b,
                            const float* __restrict__ b2b,
                            unsigned short* __restrict__ W2aT,
                            unsigned short* __restrict__ W2bT) {
    int idx = blockIdx.x * 256 + threadIdx.x;
    const int N1 = KSTEPS * NTILE * 512;   // 442368
    const int N2 = 8 * 6 * 512;            // 24576
    if (idx < N1) {
        int ks  = idx / (NTILE * 512);
        int rem = idx - ks * (NTILE * 512);
        int t   = rem >> 9;
        int q   = rem & 511;
        int ln  = q >> 3, j = q & 7;
        int kk  = ks * 16 + ((ln >> 5) << 3) + j;
        int c   = (t << 5) + (ln & 31);
        float v = 0.f;
        if (c < H2) {
            if (kk < QF)       v = W2a[kk * H2 + c];
            else if (kk == QF) v = b2a[c];
        } else if (c < H2 + H1) {
            int cc = c - H2;
            if (kk == QF)                        v = b1a[cc];
            else if (kk > QF && kk < QF + 1 + D) v = W1a[(kk - QF - 1) * H1 + cc];
        } else if (c == H2 + H1) {
            if (kk == QF) v = 1.0f;
        }
        W2aT[idx] = f2bf(v);
    } else if (idx < N1 + N2) {
        int i2 = idx - N1;
        int w  = i2 / (6 * 512);
        int rem = i2 - w * (6 * 512);
        int s  = rem >> 9;
        int q  = rem & 511;
        int ln = q >> 3, j = q & 7;
        int kg = w * 96 + s * 16 + ((ln >> 5) << 3) + j;
        int c  = ln & 31;
        float v = 0.f;
        if (kg < H2)            v = W2b[kg * D + c];
        else if (kg < H2 + H1)  v = W1b[(kg - H2) * D + c];
        else if (kg == H2 + H1) v = (b1b[c] + b2b[c]) / tanh_fast(1.0f);
        W2bT[i2] = f2bf(v);
    }
}

// ---------------- fused main kernel ----------------
// 32x32x16 MFMA version: 8 waves (512 thr), wave w owns col-tiles 3w..3w+2
// (96 hidden cols) x all 64 rows (B read once per block). A-LDS reads halve
// vs 16x16x32 (2x FLOP per A-byte); 32x32 pipe is ~15% faster per FLOP.
// acc = 6 x f32x16 = 96 VGPR at the 2-waves/SIMD 256-reg budget (LDS 134 KB
// -> 1 block/CU). Layouts: C/D row = (reg&3)+8*(reg>>2)+4*(lane>>5) (verified
// formula); A row = lane&31, k = (lane>>5)*8+j; B col = lane&31, same k.
__global__ __launch_bounds__(512)
__attribute__((amdgpu_waves_per_eu(2, 2)))
void fused_kernel(
    const float* __restrict__ y,
    const unsigned short* __restrict__ W2aT, const unsigned short* __restrict__ W2bT,
    float* __restrict__ out) {

    __shared__ unsigned short quadls[MROWS][QSTR]; // 74752 B; post-K reused: panelT [8][32][68] (34816 B)
    __shared__ float          yls[MROWS][36];      //  9216 B
    __shared__ unsigned short hst[8][32][104];     // 53248 B  => total 137216 B (1 block/CU)

    const int tid  = threadIdx.x;
    const int lane = tid & 63;
    const int w    = tid >> 6;                         // wave 0..7
    const int wu   = __builtin_amdgcn_readfirstlane(w);
    const int l31  = lane & 31;
    const int h    = lane >> 5;                        // 0..1 (k-group)
    const int row0 = blockIdx.x * MROWS;
    unsigned short* panel = &quadls[0][0];

    // ---- Phase A: y tile (float4/thread, coalesced) ----
    {
        int r = tid >> 3, c = (tid & 7) * 4;
        floatx4 v = *reinterpret_cast<const floatx4*>(y + (row0 + r) * D + c);
        *reinterpret_cast<floatx4*>(&yls[r][c]) = v;
    }
    __syncthreads();

    // ---- Phase B: A build (4 (row,i) tasks/thread): quad | 1.0 | y | pad ----
    #pragma unroll
    for (int s = 0; s < 4; ++s) {
        int task = tid + s * 512;
        int r = task >> 5, i = task & 31;
        int base = (i * (i + 1)) >> 1;
        float yi = yls[r][i];
        for (int j4 = 0; j4 <= i; j4 += 4) {
            floatx4 yv = *reinterpret_cast<const floatx4*>(&yls[r][j4]);
            #pragma unroll
            for (int jj = 0; jj < 4; ++jj) {
                int j = j4 + jj;
                if (j <= i) quadls[r][base + j] = f2bf(yi * yv[jj]);
            }
        }
        quadls[r][529 + i] = f2bf(yi);                         // y channels 529..560
        if (i == 0)  quadls[r][528] = (unsigned short)0x3F80;  // bias-one channel
        if (i < 15)  quadls[r][561 + i] = 0;                   // K-pad 561..575
    }
    __syncthreads();

    // ---- K-loop: 36 steps of K=16; 2 row-tiles x 3 col-tiles per wave ----
    floatx16 acc[2][3];
    #pragma unroll
    for (int m = 0; m < 2; ++m)
        #pragma unroll
        for (int t = 0; t < 3; ++t)
            acc[m][t] = (floatx16)(0.f);
    {
        const unsigned short* bp = W2aT + wu * 3 * 512 + lane * 8;
        #pragma unroll 2
        for (int ks = 0; ks < KSTEPS; ++ks) {
            short8x a0 = *reinterpret_cast<const short8x*>(&quadls[l31][ks * 16 + h * 8]);
            short8x a1 = *reinterpret_cast<const short8x*>(&quadls[32 + l31][ks * 16 + h * 8]);
            short8x b0 = *reinterpret_cast<const short8x*>(bp);
            short8x b1 = *reinterpret_cast<const short8x*>(bp + 512);
            short8x b2 = *reinterpret_cast<const short8x*>(bp + 1024);
            acc[0][0] = __builtin_amdgcn_mfma_f32_32x32x16_bf16(a0, b0, acc[0][0], 0, 0, 0);
            acc[0][1] = __builtin_amdgcn_mfma_f32_32x32x16_bf16(a0, b1, acc[0][1], 0, 0, 0);
            acc[0][2] = __builtin_amdgcn_mfma_f32_32x32x16_bf16(a0, b2, acc[0][2], 0, 0, 0);
            acc[1][0] = __builtin_amdgcn_mfma_f32_32x32x16_bf16(a1, b0, acc[1][0], 0, 0, 0);
            acc[1][1] = __builtin_amdgcn_mfma_f32_32x32x16_bf16(a1, b1, acc[1][1], 0, 0, 0);
            acc[1][2] = __builtin_amdgcn_mfma_f32_32x32x16_bf16(a1, b2, acc[1][2], 0, 0, 0);
            bp += NTILE * 512;
        }
    }
    __syncthreads();   // all quadls K-reads complete -> panel region free

    // ---- epilogue: 2 row-tile passes: tanh -> hst -> GEMM2 -> packed panel ----
    {
        const unsigned short* wb = W2bT + wu * 6 * 512 + lane * 8;
        short8x bw[6];
        #pragma unroll
        for (int s = 0; s < 6; ++s)
            bw[s] = *reinterpret_cast<const short8x*>(wb + s * 512);

        #pragma unroll
        for (int m = 0; m < 2; ++m) {
            // tanh(h) into hst[w]: row=(reg&3)+8*(reg>>2)+4h, col=t*32+l31
            #pragma unroll
            for (int t = 0; t < 3; ++t)
                #pragma unroll
                for (int reg = 0; reg < 16; ++reg)
                    hst[w][(reg & 3) + 8 * (reg >> 2) + 4 * h][t * 32 + l31]
                        = f2bf(tanh_fast(acc[m][t][reg]));
            // GEMM2: C2 += h[32 x 96] @ B2[96 x 32]
            floatx16 o2 = (floatx16)(0.f);
            #pragma unroll
            for (int s = 0; s < 6; ++s) {
                short8x a2 = *reinterpret_cast<const short8x*>(&hst[w][l31][s * 16 + h * 8]);
                o2 = __builtin_amdgcn_mfma_f32_32x32x16_bf16(a2, bw[s], o2, 0, 0, 0);
            }
            // pack 4 rows per b64 into transposed panel [w][col 32][row 68-stride]
            #pragma unroll
            for (int q = 0; q < 4; ++q) {
                ushort4x pk;
                #pragma unroll
                for (int i = 0; i < 4; ++i)
                    pk[i] = f2bf(o2[4 * q + i]);
                *reinterpret_cast<ushort4x*>(
                    &panel[wu * 2176 + l31 * 68 + m * 32 + 8 * q + 4 * h]) = pk;
            }
        }
    }
    __syncthreads();   // all panel writes visible

    // ---- reduce 8 bf16 panels (biases inside): 4 outputs/thread ----
    {
        int c  = tid & 31;          // output col
        int rg = tid >> 5;          // row group 0..15 (rows rg*4..rg*4+3)
        int base = c * 68 + rg * 4;
        float s0 = 0.f, s1 = 0.f, s2 = 0.f, s3 = 0.f;
        #pragma unroll
        for (int p = 0; p < 8; ++p) {
            ushort4x v = *reinterpret_cast<const ushort4x*>(&panel[p * 2176 + base]);
            s0 += bf2f(v[0]); s1 += bf2f(v[1]); s2 += bf2f(v[2]); s3 += bf2f(v[3]);
        }
        out[(row0 + rg * 4 + 0) * D + c] = s0;
        out[(row0 + rg * 4 + 1) * D + c] = s1;
        out[(row0 + rg * 4 + 2) * D + c] = s2;
        out[(row0 + rg * 4 + 3) * D + c] = s3;
    }
}

extern "C" void kernel_launch(void* const* d_in, const int* in_sizes, int n_in,
                              void* d_out, int out_size, void* d_ws, size_t ws_size,
                              hipStream_t stream) {
    const float* y   = (const float*)d_in[1];
    const float* W1a = (const float*)d_in[2];
    const float* b1a = (const float*)d_in[3];
    const float* W1b = (const float*)d_in[4];
    const float* b1b = (const float*)d_in[5];
    const float* W2a = (const float*)d_in[6];
    const float* b2a = (const float*)d_in[7];
    const float* W2b = (const float*)d_in[8];
    const float* b2b = (const float*)d_in[9];

    unsigned short* W2aT = (unsigned short*)d_ws;                      // 884736 B
    unsigned short* W2bT = (unsigned short*)((char*)d_ws + 884736);    //  49152 B

    const int prep_tasks = KSTEPS * NTILE * 512 + 8 * 6 * 512;         // 466944
    prep_kernel<<<(prep_tasks + 255) / 256, 256, 0, stream>>>(
        W2a, b2a, W2b, W1a, b1a, W1b, b1b, b2b, W2aT, W2bT);
    fused_kernel<<<B_TOT / MROWS, 512, 0, stream>>>(y, W2aT, W2bT, (float*)d_out);
}

// Round 19
// 151.750 us; speedup vs baseline: 1.1741x; 1.1741x over previous
//
#include <hip/hip_runtime.h>
#include <hip/hip_bf16.h>

#define B_TOT 131072
#define D     32
#define H1    50
#define QF    528      // tril feature count
#define H2    700
#define MROWS 64       // batch rows per block
#define QSTR  584      // quadls row stride (ushorts)
#define KITER 18       // K = 576 = 528 quad | 1 bias-one | 32 y | 15 pad
// extended hidden layout (768 cols): 0..699 net2 hidden, 700..749 net1 hidden,
// 750 bias channel (h==1.0), 751..767 zero pad

typedef __attribute__((ext_vector_type(8))) short  short8x;
typedef __attribute__((ext_vector_type(4))) float  floatx4;
typedef __attribute__((ext_vector_type(4))) unsigned int uint4x;

static __device__ __forceinline__ unsigned short f2bf(float f) {
    __hip_bfloat16 h = __float2bfloat16(f);   // RNE
    return __builtin_bit_cast(unsigned short, h);
}
static __device__ __forceinline__ float bf2f(unsigned short u) {
    unsigned int x = (unsigned int)u << 16;
    return __builtin_bit_cast(float, x);
}
// clampless tanh; MUST stay bit-identical between prep (bias channel) and epilogue.
static __device__ __forceinline__ float tanh_fast(float x) {
    float e = __builtin_amdgcn_exp2f(x * 2.885390082f);   // e^(2x)
    return 1.f - 2.f * __builtin_amdgcn_rcpf(e + 1.f);
}

// ---------------- prep: extended pre-fragmented bf16 weight layouts (r11, unchanged) ----
__global__ void prep_kernel(const float* __restrict__ W2a, const float* __restrict__ b2a,
                            const float* __restrict__ W2b,
                            const float* __restrict__ W1a, const float* __restrict__ b1a,
                            const float* __restrict__ W1b, const float* __restrict__ b1b,
                            const float* __restrict__ b2b,
                            unsigned short* __restrict__ W2aT,
                            unsigned short* __restrict__ W2bT) {
    int idx = blockIdx.x * 256 + threadIdx.x;
    const int N1 = KITER * 48 * 512;   // 442368
    const int N2 = 16 * 4 * 512;       // 32768
    if (idx < N1) {
        int k   = idx / (48 * 512);
        int rem = idx - k * (48 * 512);
        int p   = rem >> 9;
        int q   = rem & 511;
        int ln  = q >> 3, j = q & 7;
        int kk  = k * 32 + ((ln >> 4) << 3) + j;
        int c   = (p << 4) + (ln & 15);
        float v = 0.f;
        if (c < H2) {
            if (kk < QF)       v = W2a[kk * H2 + c];
            else if (kk == QF) v = b2a[c];
        } else if (c < H2 + H1) {
            int cc = c - H2;
            if (kk == QF)                        v = b1a[cc];
            else if (kk > QF && kk < QF + 1 + D) v = W1a[(kk - QF - 1) * H1 + cc];
        } else if (c == H2 + H1) {
            if (kk == QF) v = 1.0f;
        }
        W2aT[idx] = f2bf(v);
    } else if (idx < N1 + N2) {
        int i2 = idx - N1;
        int q  = i2 & 511;
        int ln = q >> 3, j = q & 7;
        int w  = i2 >> 11;
        int ks = (i2 >> 10) & 1;
        int of = (i2 >> 9) & 1;
        int kl = (ks << 5) + ((ln >> 4) << 3) + j;   // local k 0..63
        int kg = w * 48 + kl;
        int c  = (of << 4) + (ln & 15);
        float v = 0.f;
        if (kl < 48) {
            if (kg < H2)            v = W2b[kg * D + c];
            else if (kg < H2 + H1)  v = W1b[(kg - H2) * D + c];
            else if (kg == H2 + H1) v = (b1b[c] + b2b[c]) / tanh_fast(1.0f);
        }
        W2bT[i2] = f2bf(v);
    }
}

// ---------------- fused main kernel ----------------
// r17 base (measured family optimum: 64 rows, 16 waves, 4 waves/SIMD) with
// the last safe cuts:
//  - yls deleted: y read straight from global in the build (8 KB tile is
//    L1-resident; row-reads broadcast, yi coalesced). Phase-A barrier gone
//    (4 -> 3 barriers). [net1 folding made yls single-use]
//  - K-loop unroll 3 (9 B-loads in flight, +~24 VGPR, under the 128 budget).
// r18's decisive lesson: binding constraint is waves/SIMD latency hiding,
// not LDS throughput (halving LDS traffic at 2 waves/SIMD lost 24%).
__global__ __launch_bounds__(1024)
__attribute__((amdgpu_waves_per_eu(4, 4)))
void fused_kernel(
    const float* __restrict__ y,
    const unsigned short* __restrict__ W2aT, const unsigned short* __restrict__ W2bT,
    float* __restrict__ out) {

    __shared__ unsigned short quadls[MROWS][QSTR]; // 74752 B; post-K reused as bf16 stage [16][2048]
    __shared__ unsigned short hst[16][16][72];     // 36864 B  => total 111616 B (1 block/CU)

    const int tid  = threadIdx.x;
    const int lane = tid & 63;
    const int w    = tid >> 6;                         // wave 0..15
    const int wu   = __builtin_amdgcn_readfirstlane(w);
    const int l15  = lane & 15;
    const int lg   = lane >> 4;                        // 0..3
    const int row0 = blockIdx.x * MROWS;
    unsigned short* stage = &quadls[0][0];

    // ---- hst K-pad cols 48..63 zero (wave-local; consumed only by this wave) ----
    {
        int rr = lane >> 2, cc0 = 48 + (lane & 3) * 4;
        *reinterpret_cast<unsigned long long*>(&hst[w][rr][cc0]) = 0ULL;
    }

    // ---- Phase B: A build straight from global y (no yls staging) ----
    // 2 (row,i) tasks/thread: quad | 1.0 | y | pad
    #pragma unroll
    for (int s = 0; s < 2; ++s) {
        int task = tid + s * 1024;
        int r = task >> 5, i = task & 31;
        const float* yr = y + (row0 + r) * D;
        int base = (i * (i + 1)) >> 1;
        float yi = yr[i];
        for (int j4 = 0; j4 <= i; j4 += 4) {
            floatx4 yv = *reinterpret_cast<const floatx4*>(yr + j4);
            #pragma unroll
            for (int jj = 0; jj < 4; ++jj) {
                int j = j4 + jj;
                if (j <= i) quadls[r][base + j] = f2bf(yi * yv[jj]);
            }
        }
        quadls[r][529 + i] = f2bf(yi);                         // y channels 529..560
        if (i == 0)  quadls[r][528] = (unsigned short)0x3F80;  // bias-one channel
        if (i < 15)  quadls[r][561 + i] = 0;                   // K-pad 561..575
    }
    __syncthreads();

    // ---- K-loop: wave w owns hidden cols [w*48, w*48+48) x 64 rows, K=576 ----
    floatx4 hacc[4][3];
    #pragma unroll
    for (int m = 0; m < 4; ++m)
        #pragma unroll
        for (int nf = 0; nf < 3; ++nf) hacc[m][nf] = (floatx4){0.f, 0.f, 0.f, 0.f};
    {
        const unsigned short* bp = W2aT + wu * 3 * 512 + lane * 8;
        #pragma unroll 3
        for (int k = 0; k < KITER; ++k) {
            short8x a[4];
            #pragma unroll
            for (int m = 0; m < 4; ++m)
                a[m] = *reinterpret_cast<const short8x*>(&quadls[m * 16 + l15][k * 32 + lg * 8]);
            short8x b0 = *reinterpret_cast<const short8x*>(bp);
            short8x b1 = *reinterpret_cast<const short8x*>(bp + 512);
            short8x b2 = *reinterpret_cast<const short8x*>(bp + 1024);
            #pragma unroll
            for (int m = 0; m < 4; ++m) {
                hacc[m][0] = __builtin_amdgcn_mfma_f32_16x16x32_bf16(a[m], b0, hacc[m][0], 0, 0, 0);
                hacc[m][1] = __builtin_amdgcn_mfma_f32_16x16x32_bf16(a[m], b1, hacc[m][1], 0, 0, 0);
                hacc[m][2] = __builtin_amdgcn_mfma_f32_16x16x32_bf16(a[m], b2, hacc[m][2], 0, 0, 0);
            }
            bp += 48 * 512;
        }
    }
    __syncthreads();   // all quadls K-reads complete -> stage region free

    // ---- epilogue: per m-tile: tanh -> hst -> GEMM2 (transient o2) -> b128 stage ----
    // stage layout (ushort idx in panel wu): (row&~3)*32 + c*8 + (row&3)*2 + of
    {
        const unsigned short* wb = W2bT + wu * 4 * 512 + lane * 8;
        #pragma unroll
        for (int m = 0; m < 4; ++m) {
            #pragma unroll
            for (int r = 0; r < 4; ++r) {
                hst[w][lg * 4 + r][l15]      = f2bf(tanh_fast(hacc[m][0][r]));
                hst[w][lg * 4 + r][16 + l15] = f2bf(tanh_fast(hacc[m][1][r]));
                hst[w][lg * 4 + r][32 + l15] = f2bf(tanh_fast(hacc[m][2][r]));
            }
            short8x aa0 = *reinterpret_cast<const short8x*>(&hst[w][l15][lg * 8]);
            short8x aa1 = *reinterpret_cast<const short8x*>(&hst[w][l15][32 + lg * 8]);
            floatx4 o20 = {0,0,0,0}, o21 = {0,0,0,0};
            {
                short8x bw00 = *reinterpret_cast<const short8x*>(wb);
                short8x bw01 = *reinterpret_cast<const short8x*>(wb + 512);
                o20 = __builtin_amdgcn_mfma_f32_16x16x32_bf16(aa0, bw00, o20, 0, 0, 0);
                o21 = __builtin_amdgcn_mfma_f32_16x16x32_bf16(aa0, bw01, o21, 0, 0, 0);
            }
            {
                short8x bw10 = *reinterpret_cast<const short8x*>(wb + 1024);
                short8x bw11 = *reinterpret_cast<const short8x*>(wb + 1536);
                o20 = __builtin_amdgcn_mfma_f32_16x16x32_bf16(aa1, bw10, o20, 0, 0, 0);
                o21 = __builtin_amdgcn_mfma_f32_16x16x32_bf16(aa1, bw11, o21, 0, 0, 0);
            }
            uint4x pk;
            #pragma unroll
            for (int r = 0; r < 4; ++r)
                pk[r] = ((unsigned int)f2bf(o21[r]) << 16) | (unsigned int)f2bf(o20[r]);
            *reinterpret_cast<uint4x*>(
                &stage[wu * 2048 + (m * 16 + lg * 4) * 32 + l15 * 8]) = pk;
        }
    }
    __syncthreads();   // all stage writes visible

    // ---- reduce 16 bf16 panels: 1 packed u32/panel -> both output cols ----
    {
        int row = tid >> 4, c = tid & 15;
        int fr = (row & ~3) * 32 + c * 8 + (row & 3) * 2;    // ushort idx of pk
        float a0 = 0.f, a1 = 0.f, a2 = 0.f, a3 = 0.f;        // col c chains
        float b0 = 0.f, b1 = 0.f, b2 = 0.f, b3 = 0.f;        // col c+16 chains
        #pragma unroll
        for (int p = 0; p < 16; p += 4) {
            unsigned int v0 = *reinterpret_cast<const unsigned int*>(&stage[p * 2048 + fr]);
            unsigned int v1 = *reinterpret_cast<const unsigned int*>(&stage[(p + 1) * 2048 + fr]);
            unsigned int v2 = *reinterpret_cast<const unsigned int*>(&stage[(p + 2) * 2048 + fr]);
            unsigned int v3 = *reinterpret_cast<const unsigned int*>(&stage[(p + 3) * 2048 + fr]);
            a0 += bf2f((unsigned short)(v0 & 0xffff));  b0 += bf2f((unsigned short)(v0 >> 16));
            a1 += bf2f((unsigned short)(v1 & 0xffff));  b1 += bf2f((unsigned short)(v1 >> 16));
            a2 += bf2f((unsigned short)(v2 & 0xffff));  b2 += bf2f((unsigned short)(v2 >> 16));
            a3 += bf2f((unsigned short)(v3 & 0xffff));  b3 += bf2f((unsigned short)(v3 >> 16));
        }
        out[row0 * D + row * 32 + c]      = (a0 + a1) + (a2 + a3);
        out[row0 * D + row * 32 + c + 16] = (b0 + b1) + (b2 + b3);
    }
}

extern "C" void kernel_launch(void* const* d_in, const int* in_sizes, int n_in,
                              void* d_out, int out_size, void* d_ws, size_t ws_size,
                              hipStream_t stream) {
    const float* y   = (const float*)d_in[1];
    const float* W1a = (const float*)d_in[2];
    const float* b1a = (const float*)d_in[3];
    const float* W1b = (const float*)d_in[4];
    const float* b1b = (const float*)d_in[5];
    const float* W2a = (const float*)d_in[6];
    const float* b2a = (const float*)d_in[7];
    const float* W2b = (const float*)d_in[8];
    const float* b2b = (const float*)d_in[9];

    unsigned short* W2aT = (unsigned short*)d_ws;                      // 884736 B
    unsigned short* W2bT = (unsigned short*)((char*)d_ws + 884736);    //  65536 B

    const int prep_tasks = KITER * 48 * 512 + 16 * 4 * 512;            // 475136
    prep_kernel<<<(prep_tasks + 255) / 256, 256, 0, stream>>>(
        W2a, b2a, W2b, W1a, b1a, W1b, b1b, b2b, W2aT, W2bT);
    fused_kernel<<<B_TOT / MROWS, 1024, 0, stream>>>(y, W2aT, W2bT, (float*)d_out);
}